// Round 21
// baseline (668.600 us; speedup 1.0000x reference)
//
#include <hip/hip_runtime.h>
#include <hip/hip_fp16.h>
#include <stdint.h>

// SymmetricQuantLinear: out[m,n] = scale[n] * sum_k x[m,k] * (nib(k,n) - 8)
// Round 21: 128x256 tile, BK=32, 8 waves (2Mx4N, 64x64 out each).
//   Per-wave regs: acc 64 AGPR + frags 32 VGPR -> unified ~124 <= 128
//   -> 2 blocks/CU, 4 waves/SIMD (cross-block issue diversity — the
//   mechanism R16's 256² tile structurally forbids).
//   1 barrier/tile; 3 staging units (8KB) issued right after entry BAR
//   (full-tile lead); WAITV(0) drains only 1-tile-old units.
//   R10 swizzle (0-conflict), R14 XCD map (4 M-rows/XCD), prepasses as ever.

#define M_DIM 4096
#define K_DIM 4096
#define N_DIM 11008
#define KH    (K_DIM / 2)

#define WS_XH_BYTES  ((size_t)M_DIM * K_DIM * 2)            // 32 MiB

typedef __attribute__((ext_vector_type(8))) _Float16 f16x8;
typedef __attribute__((ext_vector_type(2))) _Float16 h2;
typedef __attribute__((ext_vector_type(4))) float f32x4;

__device__ __forceinline__ unsigned pack_f16_pair(float lo, float hi) {
    return __builtin_bit_cast(unsigned, __builtin_amdgcn_cvt_pkrtz(lo, hi));
}

__device__ __forceinline__ unsigned dq_pair(unsigned v) {
    unsigned c = (v & 0xFu) | ((v << 12) & 0x000F0000u) | 0x64006400u;
    h2 r = __builtin_bit_cast(h2, c) + __builtin_bit_cast(h2, 0xE408E408u);
    return __builtin_bit_cast(unsigned, r);
}

__device__ __forceinline__ void gld_lds16(const void* g, void* l) {
    __builtin_amdgcn_global_load_lds(
        (const __attribute__((address_space(1))) unsigned int*)g,
        (__attribute__((address_space(3))) unsigned int*)l,
        16, 0, 0);
}

// ---- Pass 1a: X f32 -> fp16 (exact) ----
__global__ void __launch_bounds__(256) cvt_x_kernel(
    const float* __restrict__ X, unsigned short* __restrict__ Xh)
{
    size_t i = ((size_t)blockIdx.x * 256 + threadIdx.x) * 8;
    float4 a = *(const float4*)(X + i);
    float4 b = *(const float4*)(X + i + 4);
    uint4 o = make_uint4(pack_f16_pair(a.x, a.y), pack_f16_pair(a.z, a.w),
                         pack_f16_pair(b.x, b.y), pack_f16_pair(b.z, b.w));
    *(uint4*)(Xh + i) = o;
}

// ---- Pass 1b: WP [KH][N] -> Wt uint32 [N][KH] ----
__global__ void __launch_bounds__(256) dqt_kernel(
    const int* __restrict__ WP, unsigned* __restrict__ Wt)
{
    __shared__ unsigned Lt[64][65];
    const int t = threadIdx.x;
    const int n0 = blockIdx.x * 64;
    const int r0 = blockIdx.y * 64;
    const int g = t >> 6, l = t & 63;
#pragma unroll
    for (int i = 0; i < 16; ++i) {
        const int r = r0 + g * 16 + i;
        Lt[l][g * 16 + i] = dq_pair((unsigned)WP[(size_t)r * N_DIM + n0 + l]);
    }
    __syncthreads();
    const int nr = t >> 2, sg = t & 3;
    unsigned* dst = Wt + (size_t)(n0 + nr) * KH + r0 + sg * 16;
#pragma unroll
    for (int c = 0; c < 4; ++c) {
        uint4 v = make_uint4(Lt[nr][sg * 16 + c * 4 + 0], Lt[nr][sg * 16 + c * 4 + 1],
                             Lt[nr][sg * 16 + c * 4 + 2], Lt[nr][sg * 16 + c * 4 + 3]);
        *(uint4*)(dst + c * 4) = v;
    }
}

// ---- Pass 2: 128x256 thin-tile fp16 GEMM, 2 blocks/CU ----
__global__ void __launch_bounds__(512, 3) qgemm13_kernel(
    const unsigned short* __restrict__ Xh,   // fp16 [M][K]
    const unsigned*       __restrict__ Wt,   // uint32 [N][KH] (fp16 [N][K])
    const float*          __restrict__ WS,   // [N]
    float*                __restrict__ Out)  // f32 [M][N]
{
    __shared__ unsigned short LA[2][4096];   // [dbuf][128 rows x 32] = 16 KB
    __shared__ unsigned short LB[2][8192];   // [dbuf][256 rows x 32] = 32 KB

    const int t = threadIdx.x;     // 0..511
    const int w = t >> 6;          // wave 0..7
    const int l = t & 63;

    // XCD map: xcd owns 4 consecutive M-rows, N-major within.
    const int bid = blockIdx.x;                 // 0..1375
    const int xcd = bid & 7;
    const int i8  = bid >> 3;                   // 0..171
    const int bx  = i8 >> 2;                    // 0..42
    const int by  = (xcd << 2) | (i8 & 3);      // 0..31
    const int bm0 = by * 128;
    const int bn0 = bx * 256;

    const int wr = w >> 2;         // 0..1 -> rows wr*64
    const int wc = w & 3;          // 0..3 -> cols wc*64

    f32x4 acc[4][4];               // 64 AGPR
#pragma unroll
    for (int i = 0; i < 4; ++i)
#pragma unroll
        for (int j = 0; j < 4; ++j)
            acc[i][j] = (f32x4){0.f, 0.f, 0.f, 0.f};

    // ---- staging: 3 units of 8 KB (A; B0 rows 0-127; B1 rows 128-255) ----
    // thread t: row t>>2 (0..127), slot c0 = t&3, source slot XOR-swizzled.
    const int r0 = t >> 2;
    const int c0 = t & 3;
    const int cS = c0 ^ ((r0 >> 1) & 3);
    const unsigned short* gA  = Xh + (size_t)(bm0 + r0) * K_DIM + cS * 8;
    const unsigned*       gB0 = Wt + (size_t)(bn0 + r0) * KH + cS * 4;
    const unsigned*       gB1 = Wt + (size_t)(bn0 + 128 + r0) * KH + cS * 4;
    const int t8 = t * 8;

#define STAGE3(buf, kt) do {                                                  \
    gld_lds16(gB0 + (size_t)(kt) * 16, &LB[buf][t8]);                         \
    gld_lds16(gB1 + (size_t)(kt) * 16, &LB[buf][4096 + t8]);                  \
    gld_lds16(gA  + (size_t)(kt) * 32, &LA[buf][t8]);                         \
} while (0)

    const int lq = l >> 4;
    const int lr = l & 15;

    f16x8 af[4], bf[4];

#define READ_FR(D) do {                                                       \
    _Pragma("unroll")                                                         \
    for (int mi = 0; mi < 4; ++mi) {                                          \
        const int row = wr * 64 + mi * 16 + lr;                               \
        af[mi] = *(const f16x8*)&LA[D][row * 32 + ((lq ^ ((row >> 1) & 3)) * 8)]; \
    }                                                                         \
    _Pragma("unroll")                                                         \
    for (int ni = 0; ni < 4; ++ni) {                                          \
        const int row = wc * 64 + ni * 16 + lr;                               \
        bf[ni] = *(const f16x8*)&LB[D][row * 32 + ((lq ^ ((row >> 1) & 3)) * 8)]; \
    }                                                                         \
} while (0)

    // 16 independent MFMA (all distinct acc -> streams at full rate)
#define Q16() do {                                                            \
    __builtin_amdgcn_s_setprio(1);                                            \
    _Pragma("unroll")                                                         \
    for (int mi = 0; mi < 4; ++mi)                                            \
        _Pragma("unroll")                                                     \
        for (int ni = 0; ni < 4; ++ni)                                        \
            acc[mi][ni] = __builtin_amdgcn_mfma_f32_16x16x32_f16(             \
                af[mi], bf[ni], acc[mi][ni], 0, 0, 0);                        \
    __builtin_amdgcn_s_setprio(0);                                            \
} while (0)

#define WAITV0() asm volatile("s_waitcnt vmcnt(0)" ::: "memory")
#define LGKM0()  do { asm volatile("s_waitcnt lgkmcnt(0)" ::: "memory");      \
                      __builtin_amdgcn_sched_barrier(0); } while (0)
#define BAR()    __builtin_amdgcn_s_barrier()

    // compute tile k from buf D; stage tile kn=k+1 into DN.
    // Hazard audit: reads of DN happened in tile k-1 BEFORE its LGKM0,
    // sealed by this tile's entry BAR -> staging DN right after BAR is safe.
    // WAITV0 drains only tile k's 3 units (issued 1 full tile ago).
#define TILE_STD(D, DN, kn) do {                                              \
    WAITV0(); BAR();                                                          \
    STAGE3(DN, kn);                                                           \
    READ_FR(D); LGKM0();                                                      \
    Q16();                                                                    \
} while (0)

#define TILE_LAST(D) do {                                                     \
    WAITV0(); BAR();                                                          \
    READ_FR(D); LGKM0();                                                      \
    Q16();                                                                    \
} while (0)

    const int NT = K_DIM / 32;     // 128 tiles

    // prologue: tile 0 -> buf0
    STAGE3(0, 0);

    for (int i = 0; i < 63; ++i) {
        TILE_STD(0, 1, 2 * i + 1);        // tile 2i,   stages 2i+1
        TILE_STD(1, 0, 2 * i + 2);        // tile 2i+1, stages 2i+2
    }
    TILE_STD(0, 1, 127);                  // tile 126, stages 127
    TILE_LAST(1);                         // tile 127

    // epilogue: per-column scale, f32 store
#pragma unroll
    for (int ni = 0; ni < 4; ++ni) {
        const int col = bn0 + wc * 64 + ni * 16 + lr;
        const float s = WS[col];
#pragma unroll
        for (int mi = 0; mi < 4; ++mi) {
            const int row = bm0 + wr * 64 + mi * 16 + lq * 4;
#pragma unroll
            for (int i = 0; i < 4; ++i) {
                Out[(size_t)(row + i) * N_DIM + col] = acc[mi][ni][i] * s;
            }
        }
    }
#undef STAGE3
#undef READ_FR
#undef Q16
#undef WAITV0
#undef LGKM0
#undef BAR
#undef TILE_STD
#undef TILE_LAST
}

extern "C" void kernel_launch(void* const* d_in, const int* in_sizes, int n_in,
                              void* d_out, int out_size, void* d_ws, size_t ws_size,
                              hipStream_t stream) {
    const float* X  = (const float*)d_in[0];
    const int*   WP = (const int*)d_in[1];
    const float* WS = (const float*)d_in[2];
    float*       Out = (float*)d_out;

    unsigned short* Xh = (unsigned short*)d_ws;
    unsigned*       Wt = (unsigned*)((char*)d_ws + WS_XH_BYTES);

    cvt_x_kernel<<<(M_DIM * K_DIM) / (256 * 8), 256, 0, stream>>>(X, Xh);
    dim3 gdq(N_DIM / 64, KH / 64);                    // 172 x 32
    dqt_kernel<<<gdq, 256, 0, stream>>>(WP, Wt);
    dim3 grid((N_DIM / 256) * (M_DIM / 128));         // 43 * 32 = 1376
    qgemm13_kernel<<<grid, 512, 0, stream>>>(Xh, Wt, WS, Out);
}

// Round 22
// 406.452 us; speedup vs baseline: 1.6450x; 1.6450x over previous
//
#include <hip/hip_runtime.h>
#include <hip/hip_fp16.h>
#include <stdint.h>

// SymmetricQuantLinear: out[m,n] = scale[n] * sum_k x[m,k] * (nib(k,n) - 8)
// Round 22: R16/R20 (session best, 408us) MINUS the explicit
//   lgkmcnt(0)+sched_barrier(0) fences before MFMA clusters. Those are
//   required only for inline-asm ds_reads (rule #18); for plain-C loads
//   the compiler emits fine-grained counted lgkmcnt per consumer (m97),
//   and explicit order-pinning measurably hurts (m141). Single-variable A/B.
//   Everything else identical: counted-queue WAITV(4)/(6), 8 staging
//   units/tile, 2 barriers/tile, 0-conflict swizzle, XCD pairing, prepasses.

#define M_DIM 4096
#define K_DIM 4096
#define N_DIM 11008
#define KH    (K_DIM / 2)

#define WS_XH_BYTES  ((size_t)M_DIM * K_DIM * 2)            // 32 MiB

typedef __attribute__((ext_vector_type(8))) _Float16 f16x8;
typedef __attribute__((ext_vector_type(2))) _Float16 h2;
typedef __attribute__((ext_vector_type(4))) float f32x4;

__device__ __forceinline__ unsigned pack_f16_pair(float lo, float hi) {
    return __builtin_bit_cast(unsigned, __builtin_amdgcn_cvt_pkrtz(lo, hi));
}

__device__ __forceinline__ unsigned dq_pair(unsigned v) {
    unsigned c = (v & 0xFu) | ((v << 12) & 0x000F0000u) | 0x64006400u;
    h2 r = __builtin_bit_cast(h2, c) + __builtin_bit_cast(h2, 0xE408E408u);
    return __builtin_bit_cast(unsigned, r);
}

__device__ __forceinline__ void gld_lds16(const void* g, void* l) {
    __builtin_amdgcn_global_load_lds(
        (const __attribute__((address_space(1))) unsigned int*)g,
        (__attribute__((address_space(3))) unsigned int*)l,
        16, 0, 0);
}

// ---- Pass 1a: X f32 -> fp16 (exact) ----
__global__ void __launch_bounds__(256) cvt_x_kernel(
    const float* __restrict__ X, unsigned short* __restrict__ Xh)
{
    size_t i = ((size_t)blockIdx.x * 256 + threadIdx.x) * 8;
    float4 a = *(const float4*)(X + i);
    float4 b = *(const float4*)(X + i + 4);
    uint4 o = make_uint4(pack_f16_pair(a.x, a.y), pack_f16_pair(a.z, a.w),
                         pack_f16_pair(b.x, b.y), pack_f16_pair(b.z, b.w));
    *(uint4*)(Xh + i) = o;
}

// ---- Pass 1b: WP [KH][N] -> Wt uint32 [N][KH] ----
__global__ void __launch_bounds__(256) dqt_kernel(
    const int* __restrict__ WP, unsigned* __restrict__ Wt)
{
    __shared__ unsigned Lt[64][65];
    const int t = threadIdx.x;
    const int n0 = blockIdx.x * 64;
    const int r0 = blockIdx.y * 64;
    const int g = t >> 6, l = t & 63;
#pragma unroll
    for (int i = 0; i < 16; ++i) {
        const int r = r0 + g * 16 + i;
        Lt[l][g * 16 + i] = dq_pair((unsigned)WP[(size_t)r * N_DIM + n0 + l]);
    }
    __syncthreads();
    const int nr = t >> 2, sg = t & 3;
    unsigned* dst = Wt + (size_t)(n0 + nr) * KH + r0 + sg * 16;
#pragma unroll
    for (int c = 0; c < 4; ++c) {
        uint4 v = make_uint4(Lt[nr][sg * 16 + c * 4 + 0], Lt[nr][sg * 16 + c * 4 + 1],
                             Lt[nr][sg * 16 + c * 4 + 2], Lt[nr][sg * 16 + c * 4 + 3]);
        *(uint4*)(dst + c * 4) = v;
    }
}

// ---- Pass 2: counted-queue 8-phase fp16 GEMM (compiler-managed lgkm) ----
__global__ void __launch_bounds__(512, 2) qgemm14_kernel(
    const unsigned short* __restrict__ Xh,   // fp16 [M][K]
    const unsigned*       __restrict__ Wt,   // uint32 [N][KH] (fp16 [N][K])
    const float*          __restrict__ WS,   // [N]
    float*                __restrict__ Out)  // f32 [M][N]
{
    __shared__ unsigned short LA[2][2][8192];   // [dbuf][half][128 x 64]
    __shared__ unsigned short LB[2][2][8192];   // 128 KB total

    const int t = threadIdx.x;     // 0..511
    const int w = t >> 6;          // wave 0..7
    const int l = t & 63;

    // XCD pairing: xcd owns M-rows {2x,2x+1}, N-major (R14: FETCH 403 MB).
    const int bid = blockIdx.x;                 // 0..687
    const int xcd = bid & 7;
    const int i8  = bid >> 3;                   // 0..85
    const int bx  = i8 >> 1;                    // 0..42
    const int by  = (xcd << 1) | (i8 & 1);      // 0..15
    const int bm0 = by * 256;
    const int bn0 = bx * 256;

    const int wr = w >> 2;         // A half
    const int wc = w & 3;          // B: half = wc>>1, sub = wc&1

    f32x4 acc[8][4];
#pragma unroll
    for (int i = 0; i < 8; ++i)
#pragma unroll
        for (int j = 0; j < 4; ++j)
            acc[i][j] = (f32x4){0.f, 0.f, 0.f, 0.f};

    // staging: unit = 64 rows x 64 ushort = 8 KB = 512 threads x 16 B.
    const int cS = (t & 7) ^ ((t >> 3) & 7);
    const unsigned short* gA = Xh + (size_t)(bm0 + (t >> 3)) * K_DIM + cS * 8;
    const unsigned*       gB = Wt + (size_t)(bn0 + (t >> 3)) * KH + cS * 4;
    const int t8 = t * 8;

#define SU_A(buf, h, c, kt)                                                   \
    gld_lds16(gA + (size_t)((h) * 128 + (c) * 64) * K_DIM + (size_t)(kt) * 64, \
              &LA[buf][h][(c) * 4096 + t8])
#define SU_B(buf, bh, ch, kt)                                                 \
    gld_lds16(gB + (size_t)((bh) * 128 + (ch) * 64) * KH + (size_t)(kt) * 32, \
              &LB[buf][bh][(ch) * 4096 + t8])

    const int lq = l >> 4;
    const int lr = l & 15;

    f16x8 af0[4][2], af1[4][2], bf0[2][2], bf1[2][2];

#define READ_AF(D, h, ARR) do {                                               \
    _Pragma("unroll")                                                         \
    for (int mi = 0; mi < 4; ++mi) {                                          \
        const int lrow = (h) * 64 + mi * 16 + lr;                             \
        _Pragma("unroll")                                                     \
        for (int ks = 0; ks < 2; ++ks)                                        \
            ARR[mi][ks] = *(const f16x8*)                                     \
                &LA[D][wr][lrow * 64 + (((ks * 4 + lq) ^ (lrow & 7)) * 8)];   \
    }                                                                         \
} while (0)

#define READ_BF(D, ch, ARR) do {                                              \
    _Pragma("unroll")                                                         \
    for (int n = 0; n < 2; ++n) {                                             \
        const int lrow = (wc & 1) * 64 + (ch) * 32 + n * 16 + lr;             \
        _Pragma("unroll")                                                     \
        for (int ks = 0; ks < 2; ++ks)                                        \
            ARR[n][ks] = *(const f16x8*)                                      \
                &LB[D][wc >> 1][lrow * 64 + (((ks * 4 + lq) ^ (lrow & 7)) * 8)]; \
    }                                                                         \
} while (0)

    // 16 MFMA cluster: ks outer (dependency distance 8)
#define Q16(MB, AF, BF, NB) do {                                              \
    __builtin_amdgcn_s_setprio(1);                                            \
    _Pragma("unroll")                                                         \
    for (int ks = 0; ks < 2; ++ks)                                            \
        _Pragma("unroll")                                                     \
        for (int mi = 0; mi < 4; ++mi)                                        \
            _Pragma("unroll")                                                 \
            for (int n = 0; n < 2; ++n)                                       \
                acc[(MB) + mi][(NB) + n] =                                    \
                    __builtin_amdgcn_mfma_f32_16x16x32_f16(                   \
                        AF[mi][ks], BF[n][ks], acc[(MB) + mi][(NB) + n],      \
                        0, 0, 0);                                             \
    __builtin_amdgcn_s_setprio(0);                                            \
} while (0)

#define WAITV(n) asm volatile("s_waitcnt vmcnt(" #n ")" ::: "memory")
#define BAR()    __builtin_amdgcn_s_barrier()

    // process tile (dbuf D), stage tile ktn into DN. 2 barriers, 2 vmcnts.
    // NO explicit lgkmcnt: ds_read->MFMA ordering is value-dependence,
    // compiler emits counted lgkmcnt per consumer (m97/m141).
#define TILE_STD(D, DN, ktn) do {                                             \
    SU_B(DN, 0, 0, ktn); SU_B(DN, 0, 1, ktn);                                 \
    WAITV(4); BAR();                                                          \
    READ_AF(D, 0, af0); READ_BF(D, 0, bf0);                                   \
    Q16(0, af0, bf0, 0);                                                      \
    SU_B(DN, 1, 0, ktn); SU_B(DN, 1, 1, ktn);                                 \
    READ_BF(D, 1, bf1);                                                       \
    Q16(0, af0, bf1, 2);                                                      \
    SU_A(DN, 0, 0, ktn); SU_A(DN, 1, 0, ktn);                                 \
    WAITV(6); BAR();                                                          \
    READ_AF(D, 1, af1);                                                       \
    Q16(4, af1, bf1, 2);                                                      \
    SU_A(DN, 0, 1, ktn); SU_A(DN, 1, 1, ktn);                                 \
    Q16(4, af1, bf0, 0);                                                      \
} while (0)

#define TILE_LAST(D) do {                                                     \
    WAITV(2); BAR();                                                          \
    READ_AF(D, 0, af0); READ_BF(D, 0, bf0);                                   \
    Q16(0, af0, bf0, 0);                                                      \
    READ_BF(D, 1, bf1);                                                       \
    Q16(0, af0, bf1, 2);                                                      \
    WAITV(0); BAR();                                                          \
    READ_AF(D, 1, af1);                                                       \
    Q16(4, af1, bf1, 2);                                                      \
    Q16(4, af1, bf0, 0);                                                      \
} while (0)

    // prologue: tile 0 units in consumption order
    SU_B(0, 0, 0, 0); SU_B(0, 0, 1, 0); SU_B(0, 1, 0, 0); SU_B(0, 1, 1, 0);
    SU_A(0, 0, 0, 0); SU_A(0, 1, 0, 0); SU_A(0, 0, 1, 0); SU_A(0, 1, 1, 0);

    for (int i = 0; i < 31; ++i) {
        TILE_STD(0, 1, 2 * i + 1);        // tile 2i,   stages 2i+1
        TILE_STD(1, 0, 2 * i + 2);        // tile 2i+1, stages 2i+2
    }
    TILE_STD(0, 1, 63);                   // tile 62, stages 63
    TILE_LAST(1);                         // tile 63

    // epilogue: per-column scale, f32 store
#pragma unroll
    for (int ni = 0; ni < 4; ++ni) {
        const int col = bn0 + wc * 64 + ni * 16 + lr;
        const float s = WS[col];
#pragma unroll
        for (int mi = 0; mi < 8; ++mi) {
            const int row = bm0 + wr * 128 + mi * 16 + lq * 4;
#pragma unroll
            for (int i = 0; i < 4; ++i) {
                Out[(size_t)(row + i) * N_DIM + col] = acc[mi][ni][i] * s;
            }
        }
    }
#undef SU_A
#undef SU_B
#undef READ_AF
#undef READ_BF
#undef Q16
#undef WAITV
#undef BAR
#undef TILE_STD
#undef TILE_LAST
}

extern "C" void kernel_launch(void* const* d_in, const int* in_sizes, int n_in,
                              void* d_out, int out_size, void* d_ws, size_t ws_size,
                              hipStream_t stream) {
    const float* X  = (const float*)d_in[0];
    const int*   WP = (const int*)d_in[1];
    const float* WS = (const float*)d_in[2];
    float*       Out = (float*)d_out;

    unsigned short* Xh = (unsigned short*)d_ws;
    unsigned*       Wt = (unsigned*)((char*)d_ws + WS_XH_BYTES);

    cvt_x_kernel<<<(M_DIM * K_DIM) / (256 * 8), 256, 0, stream>>>(X, Xh);
    dim3 gdq(N_DIM / 64, KH / 64);                    // 172 x 32
    dqt_kernel<<<gdq, 256, 0, stream>>>(WP, Wt);
    dim3 grid((N_DIM / 256) * (M_DIM / 256));         // 688
    qgemm14_kernel<<<grid, 512, 0, stream>>>(Xh, Wt, WS, Out);
}